// Round 8
// baseline (194.278 us; speedup 1.0000x reference)
//
#include <hip/hip_runtime.h>
#include <hip/hip_bf16.h>

// B=4, G=1024, D=512, H=8, dh=64. NUM_BUCKETS=32, MAX_DIST=128, base=2.
typedef __attribute__((ext_vector_type(8))) short bf16x8;
typedef __attribute__((ext_vector_type(4))) float f32x4;
typedef __attribute__((ext_vector_type(16))) float f32x16;

__device__ __forceinline__ unsigned short f2bf(float x) {
  union { __hip_bfloat16 h; unsigned short u; } cv;
  cv.h = __float2bfloat16(x);
  return cv.u;
}

__device__ __forceinline__ void gload16(const void* g, void* l) {
  __builtin_amdgcn_global_load_lds(
      (const __attribute__((address_space(1))) unsigned int*)g,
      (__attribute__((address_space(3))) unsigned int*)l, 16, 0, 0);
}

// exchange a.hi-lanes with b.lo-lanes (gfx950 cross-half primitive)
__device__ __forceinline__ void pl32swap(unsigned &a, unsigned &b) {
  asm volatile("v_permlane32_swap_b32 %0, %1" : "+v"(a), "+v"(b));
}

// ---------------- fused fp32->bf16 conversion + mask prefix-scan + rank ----------
__global__ __launch_bounds__(256)
void k_cvt_scan(const float* __restrict__ q, const float* __restrict__ k,
                const float* __restrict__ v, const float* __restrict__ Wq,
                const float* __restrict__ Wk, const float* __restrict__ Wv,
                const float* __restrict__ Wo, const int* __restrict__ mask,
                unsigned short* __restrict__ XQ, unsigned short* __restrict__ XK,
                unsigned short* __restrict__ XV, unsigned short* __restrict__ WQB,
                unsigned short* __restrict__ WKB, unsigned short* __restrict__ WVB,
                unsigned short* __restrict__ WOB,
                int* __restrict__ idx, int* __restrict__ cnt, int* __restrict__ rnk)
{
  __shared__ int wsum[4];
  int bid = blockIdx.x;
  if (bid >= 3584) {
    int b = bid - 3584;
    int tdx = threadIdx.x;
    int lane = tdx & 63, w = tdx >> 6;
    int base = tdx * 4;
    int m[4]; int s = 0;
    #pragma unroll
    for (int j = 0; j < 4; ++j) { m[j] = mask[(b << 10) + base + j]; s += m[j]; }
    int x = s;
    #pragma unroll
    for (int d = 1; d < 64; d <<= 1) {
      int vv = __shfl_up(x, d);
      if (lane >= d) x += vv;
    }
    if (lane == 63) wsum[w] = x;
    __syncthreads();
    int off = 0;
    #pragma unroll
    for (int ww = 0; ww < 4; ++ww) off += (ww < w) ? wsum[ww] : 0;
    int pos = off + x - s;
    #pragma unroll
    for (int j = 0; j < 4; ++j) {
      if (m[j]) { idx[(b << 10) + pos] = base + j; rnk[(b << 10) + base + j] = pos; ++pos; }
      else      { rnk[(b << 10) + base + j] = -1; }
    }
    if (tdx == 255) cnt[b] = off + x;
    return;
  }
  long i = ((long)bid * 256 + threadIdx.x) * 8;
  const float* s; unsigned short* d; long off;
  if (i < 2097152)      { s = q; d = XQ; off = i; }
  else if (i < 4194304) { s = k; d = XK; off = i - 2097152; }
  else if (i < 6291456) { s = v; d = XV; off = i - 4194304; }
  else {
    long j = i - 6291456;
    int wsel = (int)(j >> 18);
    off = j & 262143;
    s = wsel == 0 ? Wq : wsel == 1 ? Wk : wsel == 2 ? Wv : Wo;
    d = wsel == 0 ? WQB : wsel == 1 ? WKB : wsel == 2 ? WVB : WOB;
  }
  float4 a = *(const float4*)(s + off);
  float4 bb = *(const float4*)(s + off + 4);
  bf16x8 o;
  o[0] = (short)f2bf(a.x);  o[1] = (short)f2bf(a.y);
  o[2] = (short)f2bf(a.z);  o[3] = (short)f2bf(a.w);
  o[4] = (short)f2bf(bb.x); o[5] = (short)f2bf(bb.y);
  o[6] = (short)f2bf(bb.z); o[7] = (short)f2bf(bb.w);
  *(bf16x8*)(d + off) = o;
}

// ---------------- bucket helper -------------------------------------------------
__device__ __forceinline__ int rbucket(float dd) {
  float ad = fabsf(dd);
  float n = fminf(fmaxf(ad, 1e-6f), 128.0f);
  int li = (int)floorf(logf(n) * 1.4426950408889634f);
  li = li < 0 ? 0 : (li > 31 ? 31 : li);
  int s = (dd > 0.f) ? 1 : ((dd < 0.f) ? -1 : 0);
  return li * s + 31;
}

// ---------------- compacted bucket table (crow-permuted, pad=3969) ---------------
__global__ __launch_bounds__(256)
void k_buckets(const float* __restrict__ coords,
               const int* __restrict__ idx, const int* __restrict__ cnt,
               unsigned short* __restrict__ buk)
{
  int t = threadIdx.x;
  int bid2 = blockIdx.x;
  int b = bid2 >> 12;
  int f = ((bid2 & 4095) << 8) + t;   // q*1024 + ck
  int qi = f >> 10, ck = f & 1023;
  int cn = cnt[b];
  int cnp = (cn + 63) & ~63;
  if (ck >= cnp) return;
  // crow permutation within 32-chunk: store at o so lane (q,hi) reads 2x b128
  int kq = ck & 31;
  int o = ((kq & 3) | ((kq >> 3) << 2)) + ((kq & 4) << 2);
  int pos = (ck & ~31) | o;
  unsigned short val = 3969;           // pad -> pbT[3969] = 0
  if (ck < cn) {
    int ki = idx[(b << 10) + ck];
    const float* cb = coords + (b << 11);
    float dx = cb[qi * 2]     - cb[ki * 2];
    float dy = cb[qi * 2 + 1] - cb[ki * 2 + 1];
    val = (unsigned short)(rbucket(dx) * 63 + rbucket(dy));
  }
  buk[((long)(b << 10) + qi) * 1024 + pos] = val;
}

// ---------------- GEMM core: C = A(M,512) @ Bw(N,512)^T, 128x64 tile, 4 waves ---
__device__ __forceinline__ void gemm_core64(
    const unsigned short* __restrict__ A, const unsigned short* __restrict__ Bw,
    int m0, int n0, unsigned short* ldsA, unsigned short* ldsB, f32x4 acc[4][2])
{
  const int t = threadIdx.x;
  const int lane = t & 63;
  const int w = t >> 6;
  const int wm = (w >> 1) << 6;
  const int wn = (w & 1) << 5;
  const int l15 = lane & 15;
  const int l4 = lane >> 4;
  const f32x4 fz = {0.f, 0.f, 0.f, 0.f};

  #pragma unroll
  for (int r = 0; r < 4; ++r)
    #pragma unroll
    for (int c = 0; c < 2; ++c) acc[r][c] = fz;

  for (int k0 = 0; k0 < 512; k0 += 32) {
    #pragma unroll
    for (int rr = 0; rr < 2; ++rr) {
      int c = rr * 256 + t;
      int row = c >> 2, cc = c & 3;
      gload16(A + (m0 + row) * 512 + k0 + cc * 8, (char*)ldsA + c * 16);
    }
    {
      int c = t;
      int row = c >> 2, cc = c & 3;
      gload16(Bw + (n0 + row) * 512 + k0 + cc * 8, (char*)ldsB + c * 16);
    }
    __syncthreads();
    bf16x8 af[4], bfr[2];
    #pragma unroll
    for (int r = 0; r < 4; ++r)
      af[r] = *(const bf16x8*)((const char*)ldsA + (wm + r * 16 + l15) * 64 + l4 * 16);
    #pragma unroll
    for (int c = 0; c < 2; ++c)
      bfr[c] = *(const bf16x8*)((const char*)ldsB + (wn + c * 16 + l15) * 64 + l4 * 16);
    #pragma unroll
    for (int r = 0; r < 4; ++r)
      #pragma unroll
      for (int c = 0; c < 2; ++c)
        acc[r][c] = __builtin_amdgcn_mfma_f32_16x16x32_bf16(af[r], bfr[c], acc[r][c], 0, 0, 0);
    __syncthreads();
  }
}

// ---------------- Q/K/V projections with fused compaction scatter ---------------
// z=0: QP dense (B,H,G,64). z=1: KC rows scattered to rank. z=2: VCT transposed
// (B,H,64,1024) scattered to rank column. Invalid tokens dropped (pad stays
// poison — harmless: pad buckets give p=0, making pad K/V values irrelevant).
__global__ __launch_bounds__(256)
void k_gemm_proj(const unsigned short* __restrict__ XQ, const unsigned short* __restrict__ XK,
                 const unsigned short* __restrict__ XV, const unsigned short* __restrict__ WQ,
                 const unsigned short* __restrict__ WK, const unsigned short* __restrict__ WV,
                 const float* __restrict__ bq, const float* __restrict__ bk,
                 const float* __restrict__ bv, const int* __restrict__ rnk,
                 unsigned short* __restrict__ QP, unsigned short* __restrict__ KC,
                 unsigned short* __restrict__ VCT)
{
  __shared__ unsigned short ldsA[128 * 32];
  __shared__ unsigned short ldsB[64 * 32];
  int z = blockIdx.z;
  const unsigned short* A = z == 0 ? XQ : z == 1 ? XK : XV;
  const unsigned short* W = z == 0 ? WQ : z == 1 ? WK : WV;
  const float* bias = z == 0 ? bq : z == 1 ? bk : bv;
  int m0 = blockIdx.x * 128, n0 = blockIdx.y * 64;
  f32x4 acc[4][2];
  gemm_core64(A, W, m0, n0, ldsA, ldsB, acc);

  const int t = threadIdx.x, lane = t & 63, w = t >> 6;
  const int wm = (w >> 1) << 6, wn = (w & 1) << 5;
  const int l15 = lane & 15, l4 = lane >> 4;
  #pragma unroll
  for (int r = 0; r < 4; ++r)
    #pragma unroll
    for (int c = 0; c < 2; ++c)
      #pragma unroll
      for (int i = 0; i < 4; ++i) {
        int m = m0 + wm + r * 16 + (l4 << 2) + i;   // token
        int n = n0 + wn + c * 16 + l15;             // channel
        float y = acc[r][c][i] + bias[n];
        int b = m >> 10, g = m & 1023, hh = n >> 6, dd = n & 63;
        int bh = (b << 3) | hh;
        if (z == 0) {
          QP[(((long)bh << 10) + g) * 64 + dd] = f2bf(y);
        } else {
          int rk = rnk[(b << 10) + g];
          if (rk >= 0) {
            if (z == 1) KC[(((long)bh << 10) + rk) * 64 + dd] = f2bf(y);
            else        VCT[(((long)bh << 6) + dd) * 1024 + rk] = f2bf(y);
          }
        }
      }
}

// ---------------- flash attention: 32x32 swapped-QK, in-register softmax --------
// grid 1024 x 256. Block = 32 q rows of one (b,h); 4 waves = key quarters.
// KREP=2 diagnostic: loop keys twice — doubles oacc AND lsum, so O unchanged;
// doubles dispatch time so rocprof top-5 surfaces this kernel with counters.
__global__ __launch_bounds__(256)
void k_attn(const unsigned short* __restrict__ QP, const unsigned short* __restrict__ KC,
            const unsigned short* __restrict__ VCT, const unsigned short* __restrict__ BUKP,
            const int* __restrict__ cnt, const float* __restrict__ rpe_x,
            const float* __restrict__ rpe_y, unsigned short* __restrict__ AO)
{
  __shared__ float smem[8320];               // 33.3KB: pbT[3970] aliases Omrg[4][32][64]
  float* pbT = smem;
  float (*Omrg)[32][64] = (float(*)[32][64])smem;
  float* Lmrg = smem + 8192;                 // [4][32]

  const int t = threadIdx.x;
  const int lane = t & 63;
  const int w = t >> 6;
  const int ql = lane & 31;
  const int hi = lane >> 5;
  const float SCL = 0.18033688f;             // log2e / 8

  int g = blockIdx.x;
  int qb = g & 31, b = (g >> 5) & 3, h = g >> 7;   // qb%8 -> XCD: bucket-slice locality
  int bh = (b << 3) | h;
  int q0 = qb << 5;

  // exp-bias table: pbT[j] = 2^(bias*log2e - 20*log2e); pad entry 3969 -> 0
  for (int j = t; j < 3970; j += 256) {
    int bx = (int)(j * 0.015873017f);
    int by = j - bx * 63;
    float vv = 0.f;
    if (j < 3969)
      vv = exp2f((rpe_x[bx * 8 + h] + rpe_y[by * 8 + h]) * 1.4426950408889634f
                 - 28.853900817779268f);
    pbT[j] = vv;
  }
  __syncthreads();

  // persistent Q B-fragments
  const unsigned short* Qrow = QP + ((long)(bh << 10) + q0 + ql) * 64;
  bf16x8 qf[4];
  #pragma unroll
  for (int c = 0; c < 4; ++c)
    qf[c] = *(const bf16x8*)(Qrow + c * 16 + hi * 8);

  const int cn = cnt[b];
  const int nt = (cn + 63) >> 6;
  const unsigned short* Brow = BUKP + ((long)((b << 10) + q0 + ql)) * 1024;
  const unsigned short* Vb0 = VCT + ((long)(bh << 6) + ql) * 1024;
  const unsigned short* Vb1 = Vb0 + (32 << 10);

  float lsum = 0.f;
  f32x16 oa0, oa1;
  #pragma unroll
  for (int i = 0; i < 16; ++i) { oa0[i] = 0.f; oa1[i] = 0.f; }

  for (int rep = 0; rep < 2; ++rep)
  for (int kt = w; kt < nt; kt += 4) {
    const int kb = kt << 6;
    #pragma unroll
    for (int s = 0; s < 2; ++s) {
      const int k32 = kb + (s << 5);
      const unsigned short* Kr = KC + ((long)(bh << 10) + k32 + ql) * 64 + hi * 8;
      bf16x8 kf0 = *(const bf16x8*)(Kr);
      bf16x8 kf1 = *(const bf16x8*)(Kr + 16);
      bf16x8 kf2 = *(const bf16x8*)(Kr + 32);
      bf16x8 kf3 = *(const bf16x8*)(Kr + 48);
      uint4 bk0 = *(const uint4*)(Brow + k32 + (hi << 4));
      uint4 bk1 = *(const uint4*)(Brow + k32 + (hi << 4) + 8);
      bf16x8 vf00 = *(const bf16x8*)(Vb0 + k32 + hi * 8);
      bf16x8 vf01 = *(const bf16x8*)(Vb0 + k32 + 16 + hi * 8);
      bf16x8 vf10 = *(const bf16x8*)(Vb1 + k32 + hi * 8);
      bf16x8 vf11 = *(const bf16x8*)(Vb1 + k32 + 16 + hi * 8);

      f32x16 sa;
      #pragma unroll
      for (int i = 0; i < 16; ++i) sa[i] = 0.f;
      __builtin_amdgcn_s_setprio(1);
      sa = __builtin_amdgcn_mfma_f32_32x32x16_bf16(kf0, qf[0], sa, 0, 0, 0);
      sa = __builtin_amdgcn_mfma_f32_32x32x16_bf16(kf1, qf[1], sa, 0, 0, 0);
      sa = __builtin_amdgcn_mfma_f32_32x32x16_bf16(kf2, qf[2], sa, 0, 0, 0);
      sa = __builtin_amdgcn_mfma_f32_32x32x16_bf16(kf3, qf[3], sa, 0, 0, 0);
      __builtin_amdgcn_s_setprio(0);

      unsigned bw0[4] = {bk0.x, bk0.y, bk0.z, bk0.w};
      unsigned bw1[4] = {bk1.x, bk1.y, bk1.z, bk1.w};
      float p[16];
      #pragma unroll
      for (int r = 0; r < 8; ++r) {
        unsigned bv = (r & 1) ? (bw0[r >> 1] >> 16) : (bw0[r >> 1] & 0xffff);
        p[r] = exp2f(sa[r] * SCL) * pbT[bv];
      }
      #pragma unroll
      for (int r = 8; r < 16; ++r) {
        unsigned bv = (r & 1) ? (bw1[(r - 8) >> 1] >> 16) : (bw1[(r - 8) >> 1] & 0xffff);
        p[r] = exp2f(sa[r] * SCL) * pbT[bv];
      }
      lsum += (((p[0] + p[1]) + (p[2] + p[3])) + ((p[4] + p[5]) + (p[6] + p[7])))
            + (((p[8] + p[9]) + (p[10] + p[11])) + ((p[12] + p[13]) + (p[14] + p[15])));

      union U8 { bf16x8 v; unsigned u[4]; };
      unsigned x0 = f2bf(p[0]) | ((unsigned)f2bf(p[1]) << 16);
      unsigned x1 = f2bf(p[2]) | ((unsigned)f2bf(p[3]) << 16);
      unsigned y0 = f2bf(p[4]) | ((unsigned)f2bf(p[5]) << 16);
      unsigned y1 = f2bf(p[6]) | ((unsigned)f2bf(p[7]) << 16);
      pl32swap(x0, y0);
      pl32swap(x1, y1);
      U8 pu0; pu0.u[0] = x0; pu0.u[1] = x1; pu0.u[2] = y0; pu0.u[3] = y1;
      unsigned z0 = f2bf(p[8])  | ((unsigned)f2bf(p[9])  << 16);
      unsigned z1 = f2bf(p[10]) | ((unsigned)f2bf(p[11]) << 16);
      unsigned u0 = f2bf(p[12]) | ((unsigned)f2bf(p[13]) << 16);
      unsigned u1 = f2bf(p[14]) | ((unsigned)f2bf(p[15]) << 16);
      pl32swap(z0, u0);
      pl32swap(z1, u1);
      U8 pu1; pu1.u[0] = z0; pu1.u[1] = z1; pu1.u[2] = u0; pu1.u[3] = u1;

      __builtin_amdgcn_s_setprio(1);
      oa0 = __builtin_amdgcn_mfma_f32_32x32x16_bf16(vf00, pu0.v, oa0, 0, 0, 0);
      oa0 = __builtin_amdgcn_mfma_f32_32x32x16_bf16(vf01, pu1.v, oa0, 0, 0, 0);
      oa1 = __builtin_amdgcn_mfma_f32_32x32x16_bf16(vf10, pu0.v, oa1, 0, 0, 0);
      oa1 = __builtin_amdgcn_mfma_f32_32x32x16_bf16(vf11, pu1.v, oa1, 0, 0, 0);
      __builtin_amdgcn_s_setprio(0);
    }
  }

  // lsum: add the partner half
  {
    unsigned a = __float_as_uint(lsum), bcp = a;
    pl32swap(a, bcp);
    lsum = __uint_as_float(a) + __uint_as_float(bcp);
  }

  // merge 4 key-quarter partials (pure add — static max) via LDS
  __syncthreads();                    // all waves done reading pbT (aliased)
  #pragma unroll
  for (int r = 0; r < 16; ++r) {
    Omrg[w][r][lane] = oa0[r];
    Omrg[w][16 + r][lane] = oa1[r];
  }
  if (lane < 32) Lmrg[(w << 5) + lane] = lsum;
  __syncthreads();

  float lt = Lmrg[ql] + Lmrg[32 + ql] + Lmrg[64 + ql] + Lmrg[96 + ql];
  float linv = 1.f / lt;
  float os[8];
  #pragma unroll
  for (int j = 0; j < 8; ++j) {
    int rr = (w << 3) + j;
    os[j] = (Omrg[0][rr][lane] + Omrg[1][rr][lane] +
             Omrg[2][rr][lane] + Omrg[3][rr][lane]) * linv;
  }
  int qg = q0 + ql;
  long aobase = ((long)((b << 10) + qg)) * 512 + (h << 6);
  int dbase = ((w >> 1) << 5) + ((w & 1) << 4) + (hi << 2);
  uint2 st0, st1;
  st0.x = f2bf(os[0]) | ((unsigned)f2bf(os[1]) << 16);
  st0.y = f2bf(os[2]) | ((unsigned)f2bf(os[3]) << 16);
  st1.x = f2bf(os[4]) | ((unsigned)f2bf(os[5]) << 16);
  st1.y = f2bf(os[6]) | ((unsigned)f2bf(os[7]) << 16);
  *(uint2*)(AO + aobase + dbase) = st0;
  *(uint2*)(AO + aobase + dbase + 8) = st1;
}

// ---------------- output projection: out = AO @ Wo^T + bo (fp32 out) ------------
__global__ __launch_bounds__(256)
void k_gemm_out(const unsigned short* __restrict__ AO, const unsigned short* __restrict__ WO,
                const float* __restrict__ bo, float* __restrict__ out)
{
  __shared__ unsigned short ldsA[128 * 32];
  __shared__ unsigned short ldsB[64 * 32];
  int m0 = blockIdx.x * 128, n0 = blockIdx.y * 64;
  f32x4 acc[4][2];
  gemm_core64(AO, WO, m0, n0, ldsA, ldsB, acc);

  const int t = threadIdx.x, lane = t & 63, w = t >> 6;
  const int wm = (w >> 1) << 6, wn = (w & 1) << 5;
  const int l15 = lane & 15, l4 = lane >> 4;
  #pragma unroll
  for (int r = 0; r < 4; ++r)
    #pragma unroll
    for (int c = 0; c < 2; ++c)
      #pragma unroll
      for (int i = 0; i < 4; ++i) {
        int m = m0 + wm + r * 16 + (l4 << 2) + i;
        int n = n0 + wn + c * 16 + l15;
        out[(long)m * 512 + n] = acc[r][c][i] + bo[n];
      }
}

// ---------------- launch ---------------------------------------------------------
extern "C" void kernel_launch(void* const* d_in, const int* in_sizes, int n_in,
                              void* d_out, int out_size, void* d_ws, size_t ws_size,
                              hipStream_t stream) {
  const float* q      = (const float*)d_in[0];
  const float* k      = (const float*)d_in[1];
  const float* v      = (const float*)d_in[2];
  const float* coords = (const float*)d_in[3];
  const int*   mask   = (const int*)d_in[4];
  const float* Wq     = (const float*)d_in[5];
  const float* bq     = (const float*)d_in[6];
  const float* Wk     = (const float*)d_in[7];
  const float* bk     = (const float*)d_in[8];
  const float* Wv     = (const float*)d_in[9];
  const float* bv     = (const float*)d_in[10];
  const float* Wo     = (const float*)d_in[11];
  const float* bo     = (const float*)d_in[12];
  const float* rpe_x  = (const float*)d_in[13];
  const float* rpe_y  = (const float*)d_in[14];
  float* out = (float*)d_out;

  unsigned short* WQB  = (unsigned short*)d_ws;
  unsigned short* WKB  = WQB + 262144;
  unsigned short* WVB  = WKB + 262144;
  unsigned short* WOB  = WVB + 262144;
  unsigned short* XQ   = WOB + 262144;   // 3x2097152; dead after proj
  unsigned short* XK   = XQ + 2097152;
  unsigned short* XV   = XK + 2097152;
  unsigned short* QP   = XV + 2097152;
  unsigned short* KC   = QP + 2097152;
  unsigned short* VCT  = KC + 2097152;
  unsigned short* AO   = VCT + 2097152;
  int* idxp            = (int*)(AO + 2097152);   // 4096 ints
  int* cntp            = idxp + 4096;            // 4 ints
  int* rnkp            = cntp + 4;               // 4096 ints
  unsigned short* BUKP = XQ;   // alias: written after proj consumed XQ..XV

  k_cvt_scan<<<dim3(3588), dim3(256), 0, stream>>>(q, k, v, Wq, Wk, Wv, Wo, mask,
                                                   XQ, XK, XV, WQB, WKB, WVB, WOB,
                                                   idxp, cntp, rnkp);
  k_gemm_proj<<<dim3(32, 8, 3), dim3(256), 0, stream>>>(XQ, XK, XV, WQB, WKB, WVB,
                                                        bq, bk, bv, rnkp, QP, KC, VCT);
  k_buckets<<<dim3(16384), dim3(256), 0, stream>>>(coords, idxp, cntp, BUKP);
  k_attn<<<dim3(1024), dim3(256), 0, stream>>>(QP, KC, VCT, BUKP, cntp,
                                               rpe_x, rpe_y, AO);
  k_gemm_out<<<dim3(32, 8), dim3(256), 0, stream>>>(AO, WOB, bo, out);
}